// Round 12
// baseline (289.249 us; speedup 1.0000x reference)
//
#include <hip/hip_runtime.h>

typedef __attribute__((ext_vector_type(8))) short short8v;
typedef __attribute__((ext_vector_type(4))) float f32x4;

#define DEV __device__ __forceinline__

DEV float sigmoidf_(float x){ return 1.0f/(1.0f+expf(-x)); }
DEV float siluf_(float x){ return x/(1.0f+expf(-x)); }
DEV ushort f2bf(float f){
  union{float f; unsigned u;} a; a.f = f;
  unsigned r = a.u + 0x7fffu + ((a.u >> 16) & 1u);   // RNE
  return (ushort)(r >> 16);
}

// ---------------------------------------------------------------------------
// ws layout (bytes)
//   w36   : 0          36864
//   t1    : 36864      2097152
//   t2    : 2134016    8192
//   sd3   : 2142208    8192
//   desc  : 2150400    2048
//   Wq    : 2152448    393216
//   Wq2   : 2545664    131072
//   XBf   : 2676736    33554432   x_before f32 (128,256,256) [written by fused k_qkv]
//     p36a: 2676736    18874368   (aliases XBf head; dead before k_qkv)
//     p36b: 21551104   18874368   (aliases XBf tail + Ob head; dead before k_attn)
//   Ob    : 36231168   16777216
//   sums  : 69261312   134217728  (Qs/Kb/Vb/PEf alias, dead before k_zero)
//   cnts  : 203479040  524288
// ---------------------------------------------------------------------------

__global__ void k_w36(const float* __restrict__ w1, float* __restrict__ w36){
  int i = blockIdx.x*256 + threadIdx.x;
  if (i < 9216){
    int kk = i % 9, o = (i/9) & 3, c = i / 36;
    w36[i] = w1[(o*256 + c)*9 + kk];
  }
}

// conv1 stage 1, K-split x2 (proven R8 structure)
__global__ __launch_bounds__(256) void k_c1a(const float* __restrict__ x,
    const float* __restrict__ w36, float* __restrict__ p36a, float* __restrict__ p36b){
  int pix = blockIdx.x*256 + threadIdx.x;
  int kb  = blockIdx.y;                       // wave-uniform channel half
  const float* xr = x + (size_t)pix*256 + kb*128;
  const float* wb = w36 + kb*128*36;
  float acc[36];
  #pragma unroll
  for (int j=0;j<36;++j) acc[j]=0.f;
  #pragma unroll 4
  for (int c4=0; c4<32; ++c4){
    float4 xv = *(const float4*)(xr + c4*4);
    float xs[4] = {xv.x, xv.y, xv.z, xv.w};
    #pragma unroll
    for (int e=0;e<4;++e){
      const float4* wrow = (const float4*)(wb + (size_t)(c4*4+e)*36);
      float xe = xs[e];
      #pragma unroll
      for (int jv=0;jv<9;++jv){
        float4 wv = wrow[jv];
        acc[jv*4+0] += xe*wv.x; acc[jv*4+1] += xe*wv.y;
        acc[jv*4+2] += xe*wv.z; acc[jv*4+3] += xe*wv.w;
      }
    }
  }
  float* dst = kb ? p36b : p36a;
  #pragma unroll
  for (int j=0;j<36;++j)
    dst[(size_t)j*131072 + pix] = acc[j];
}

// conv1 stage 2
__global__ __launch_bounds__(256) void k_c1b(const float* __restrict__ p36a,
    const float* __restrict__ p36b, const float* __restrict__ b1,
    float* __restrict__ t1){
  int pix = blockIdx.x*256 + threadIdx.x;     // 131072
  int xp = pix & 255, y = (pix>>8)&255, b = pix>>16;
  float a[4] = {b1[0], b1[1], b1[2], b1[3]};
  #pragma unroll
  for (int ky=0;ky<3;++ky){
    int yy = y+ky-1; if ((unsigned)yy>=256u) continue;
    #pragma unroll
    for (int kx=0;kx<3;++kx){
      int xx = xp+kx-1; if ((unsigned)xx>=256u) continue;
      int np = (b<<16) + yy*256 + xx;
      #pragma unroll
      for (int o=0;o<4;++o){
        size_t idx = (size_t)(o*9+ky*3+kx)*131072 + np;
        a[o] += p36a[idx] + p36b[idx];
      }
    }
  }
  int base = b*262144 + y*256 + xp;
  t1[base]        = siluf_(a[0]);
  t1[base+65536]  = siluf_(a[1]);
  t1[base+131072] = siluf_(a[2]);
  t1[base+196608] = siluf_(a[3]);
}

// pre-fragment a [J][256] f32 weight into bf16 MFMA lane order
__global__ void k_wq(const float* __restrict__ w, ushort* __restrict__ Wq, int nfrag){
  int i = blockIdx.x*256 + threadIdx.x;
  if (i >= nfrag) return;
  int l  = i & 63;
  int kc = (i >> 6) & 7;
  int jt = i >> 9;
  int j = jt*16 + (l & 15);
  int k = kc*32 + (l >> 4)*8;
  const float4* src = (const float4*)(w + j*256 + k);
  float4 v0 = src[0], v1 = src[1];
  union{ uint4 q; ushort u[8]; } o;
  o.u[0]=f2bf(v0.x); o.u[1]=f2bf(v0.y); o.u[2]=f2bf(v0.z); o.u[3]=f2bf(v0.w);
  o.u[4]=f2bf(v1.x); o.u[5]=f2bf(v1.y); o.u[6]=f2bf(v1.z); o.u[7]=f2bf(v1.w);
  *(uint4*)(Wq + (size_t)i*8) = o.q;
}

__global__ void k_conv2(const float* __restrict__ t1, const float* __restrict__ w2,
                        const float* __restrict__ b2, float* __restrict__ t2){
  int oidx = blockIdx.x;
  int ox = oidx & 15, oy = (oidx>>4)&15, o = (oidx>>8)&3, b = oidx>>10;
  int t = threadIdx.x;
  float acc = 0.f;
  #pragma unroll
  for (int uu=0; uu<4; ++uu){
    int u = t + uu*256;
    int ic = u >> 8, ky = (u>>4)&15, kx = u&15;
    float xv = t1[(b*4+ic)*65536 + (oy*16+ky)*256 + (ox*16+kx)];
    float wv = w2[(o*4+ic)*256 + ky*16 + kx];
    acc += xv*wv;
  }
  __shared__ float red[256];
  red[t] = acc; __syncthreads();
  for (int s=128; s>0; s>>=1){ if (t<s) red[t]+=red[t+s]; __syncthreads(); }
  if (t==0) t2[oidx] = siluf_(red[0] + b2[o]);
}

__global__ void k_conv3(const float* __restrict__ t2, const float* __restrict__ w3,
                        const float* __restrict__ b3, float* __restrict__ sd3){
  int i = blockIdx.x*256 + threadIdx.x;
  int ox = i & 15, oy = (i>>4)&15, o = (i>>8)&3, b = i>>10;
  float acc = b3[o];
  for (int ic=0; ic<4; ++ic){
    const float* src = t2 + (b*4+ic)*256;
    const float* ww  = w3 + (o*4+ic)*9;
    #pragma unroll
    for (int ky=0; ky<3; ++ky){
      int yy = oy + ky - 1; if ((unsigned)yy >= 16u) continue;
      #pragma unroll
      for (int kx=0; kx<3; ++kx){
        int xx = ox + kx - 1; if ((unsigned)xx >= 16u) continue;
        acc += src[yy*16+xx] * ww[ky*3+kx];
      }
    }
  }
  sd3[i] = acc;
}

__global__ void k_topk(const float* __restrict__ sd3, int* __restrict__ desc){
  int b = blockIdx.x, t = threadIdx.x;
  __shared__ float sc[256];
  sc[t] = sd3[(b*4+0)*256 + t];
  __syncthreads();
  float st = sc[t];
  int rank = 0;
  for (int j=0;j<256;++j){
    float sj = sc[j];
    rank += (sj > st) || (sj == st && j < t);
  }
  if (rank < 64){
    float g = sigmoidf_(sd3[(b*4+1)*256 + t]);
    int hard = (g > 0.5f) ? 1 : 0;
    float offh = sigmoidf_(sd3[(b*4+2)*256 + t]) * 16.0f - 8.0f;
    float offw = sigmoidf_(sd3[(b*4+3)*256 + t]) * 16.0f - 8.0f;
    int hoff = (int)offh, woff = (int)offw;
    int h1 = min(max((t>>4)*16 + hoff, 0), 240);
    int w1 = min(max((t&15)*16 + woff, 0), 240);
    ((int4*)desc)[b*64 + rank] = make_int4(h1, w1, hard, 0);
  }
}

// QKV GEMM, bf16 MFMA, FUSED bilinear gather (k_xb eliminated).
// Staging computes x_before in fp32 (bitwise same expr as old k_xb),
// stores fp32 to XBf (for k_oproj delta) and bf16 to LDS (MFMA A operand).
__global__ __launch_bounds__(256) void k_qkv(const float* __restrict__ x,
    const ushort* __restrict__ Wq, const float* __restrict__ in_b,
    const int* __restrict__ desc, ushort* __restrict__ Qs,
    ushort* __restrict__ Kb, ushort* __restrict__ Vb,
    float* __restrict__ XBf){
  int wi = blockIdx.x;
  int4 d = ((const int4*)desc)[wi];
  if (!d.z) return;
  int b = wi >> 6;
  int t0 = blockIdx.y * 32;
  __shared__ __align__(16) ushort Xs[32*264];
  int tid = threadIdx.x;
  #pragma unroll
  for (int it = 0; it < 8; ++it){
    int i = tid + it*256;
    int row = i >> 6;                 // 0..31
    int chq = (i & 63) * 4;           // channel quad
    int token = t0 + row;
    int ty = token >> 4, tx = token & 15;
    float yyf = fminf((float)(d.x + ty) + 0.5f, 255.0f);
    int y0 = (int)yyf; float ly = yyf - (float)y0; int y1 = min(y0+1, 255);
    float xxf = fminf((float)(d.y + tx) + 0.5f, 255.0f);
    int x0 = (int)xxf; float lx = xxf - (float)x0; int x1 = min(x0+1, 255);
    float w00=(1.f-ly)*(1.f-lx), w01=(1.f-ly)*lx, w10=ly*(1.f-lx), w11=ly*lx;
    const float* p00 = x + ((size_t)((b*256+y0)*256 + x0))*256 + chq;
    const float* p01 = x + ((size_t)((b*256+y0)*256 + x1))*256 + chq;
    const float* p10 = x + ((size_t)((b*256+y1)*256 + x0))*256 + chq;
    const float* p11 = x + ((size_t)((b*256+y1)*256 + x1))*256 + chq;
    float4 A = *(const float4*)p00, Bv = *(const float4*)p01,
           Cv = *(const float4*)p10, Dv = *(const float4*)p11;
    float4 r;
    r.x = w00*A.x + w01*Bv.x + w10*Cv.x + w11*Dv.x;
    r.y = w00*A.y + w01*Bv.y + w10*Cv.y + w11*Dv.y;
    r.z = w00*A.z + w01*Bv.z + w10*Cv.z + w11*Dv.z;
    r.w = w00*A.w + w01*Bv.w + w10*Cv.w + w11*Dv.w;
    *(float4*)(XBf + ((size_t)(wi*256 + token))*256 + chq) = r;
    ushort4 u = make_ushort4(f2bf(r.x), f2bf(r.y), f2bf(r.z), f2bf(r.w));
    *(ushort4*)(&Xs[row*264 + chq]) = u;
  }
  __syncthreads();
  int w = tid >> 6, l = tid & 63;
  int lr = l & 15, lg = l >> 4;
  f32x4 acc[2][12];
  #pragma unroll
  for (int a=0;a<2;++a)
    #pragma unroll
    for (int j=0;j<12;++j) acc[a][j] = (f32x4){0.f,0.f,0.f,0.f};
  for (int kc = 0; kc < 8; ++kc){
    short8v xf0 = *(const short8v*)(&Xs[lr*264       + kc*32 + lg*8]);
    short8v xf1 = *(const short8v*)(&Xs[(16+lr)*264 + kc*32 + lg*8]);
    #pragma unroll
    for (int jt = 0; jt < 12; ++jt){
      short8v wf = *(const short8v*)(Wq + ((size_t)((w*12 + jt)*8 + kc)*64 + l)*8);
      acc[0][jt] = __builtin_amdgcn_mfma_f32_16x16x32_bf16(xf0, wf, acc[0][jt], 0, 0, 0);
      acc[1][jt] = __builtin_amdgcn_mfma_f32_16x16x32_bf16(xf1, wf, acc[1][jt], 0, 0, 0);
    }
  }
  #pragma unroll
  for (int ts=0; ts<2; ++ts)
    #pragma unroll
    for (int jt=0; jt<12; ++jt){
      int j = w*192 + jt*16 + lr;
      #pragma unroll
      for (int r=0; r<4; ++r){
        int t = t0 + ts*16 + lg*4 + r;
        float val = acc[ts][jt][r] + in_b[j];
        if (j < 256){
          Qs[((size_t)(wi*256 + t))*256 + j] = f2bf(val * 0.17677669529663687f);
        } else if (j < 512){
          int jq = j - 256;
          Kb[((size_t)(wi*8 + (jq>>5))*256 + t)*32 + (jq&31)] = f2bf(val);
        } else {
          int jq = j - 512;
          Vb[((size_t)(wi*8 + (jq>>5))*256 + t)*32 + (jq&31)] = f2bf(val);
        }
      }
    }
}

// PE table expanded to [h][q][j] f32
__global__ void k_pe(const float* __restrict__ pe_table, float* __restrict__ PEf){
  int id = blockIdx.x*256 + threadIdx.x;    // 524288
  int h = id >> 16, q = (id>>8)&255, j = id&255;
  int ih = (q>>4) - (j>>4) + 15;
  int iw = (q&15) - (j&15) + 15;
  PEf[id] = pe_table[(ih*31+iw)*8 + h];
}

// MFMA bf16 attention
__global__ __launch_bounds__(256,2) void k_attn(const ushort* __restrict__ Qs,
    const ushort* __restrict__ Kb, const ushort* __restrict__ Vb,
    const float* __restrict__ PEf, const int* __restrict__ desc,
    ushort* __restrict__ Ob){
  int wi = blockIdx.x, h = blockIdx.y;
  if (((const int4*)desc)[wi].z == 0) return;
  __shared__ __align__(16) ushort Ks[256*40];
  __shared__ __align__(16) ushort Vt[32*264];
  __shared__ __align__(16) ushort Pb[4][16*40];
  int tid = threadIdx.x;
  {
    const uint4* src = (const uint4*)(Kb + (size_t)((wi*8+h)*256 + tid)*32);
    uint4 a = src[0], b = src[1], c = src[2], d = src[3];
    *(uint4*)(&Ks[tid*40 +  0]) = a;
    *(uint4*)(&Ks[tid*40 +  8]) = b;
    *(uint4*)(&Ks[tid*40 + 16]) = c;
    *(uint4*)(&Ks[tid*40 + 24]) = d;
  }
  {
    const uint4* src = (const uint4*)(Vb + (size_t)((wi*8+h)*256 + tid)*32);
    #pragma unroll
    for (int c4=0; c4<4; ++c4){
      union{uint4 v; ushort u[8];} uu; uu.v = src[c4];
      #pragma unroll
      for (int e=0;e<8;++e) Vt[(c4*8+e)*264 + tid] = uu.u[e];
    }
  }
  __syncthreads();
  int w = tid >> 6, l = tid & 63;
  int lg = l >> 4, lr = l & 15;
  const float* PEh = PEf + h*65536;
  for (int s_i = 0; s_i < 4; ++s_i){
    int q0 = (w*4 + s_i)*16;
    short8v qf = *(const short8v*)(Qs + ((size_t)(wi*256 + q0 + lr))*256 + h*32 + lg*8);
    f32x4 sfr[16];
    #pragma unroll
    for (int jt=0; jt<16; ++jt){
      f32x4 c;
      #pragma unroll
      for (int r=0;r<4;++r) c[r] = PEh[(q0 + lg*4 + r)*256 + jt*16 + lr];
      short8v kf = *(const short8v*)(&Ks[(jt*16 + lr)*40 + lg*8]);
      sfr[jt] = __builtin_amdgcn_mfma_f32_16x16x32_bf16(qf, kf, c, 0, 0, 0);
    }
    float mx[4] = {-1e30f,-1e30f,-1e30f,-1e30f};
    #pragma unroll
    for (int jt=0;jt<16;++jt)
      #pragma unroll
      for (int r=0;r<4;++r) mx[r] = fmaxf(mx[r], sfr[jt][r]);
    #pragma unroll
    for (int m_=1; m_<16; m_<<=1){
      #pragma unroll
      for (int r=0;r<4;++r) mx[r] = fmaxf(mx[r], __shfl_xor(mx[r], m_));
    }
    float sm[4] = {0.f,0.f,0.f,0.f};
    #pragma unroll
    for (int jt=0;jt<16;++jt)
      #pragma unroll
      for (int r=0;r<4;++r){
        float p = __expf(sfr[jt][r] - mx[r]);
        sfr[jt][r] = p; sm[r] += p;
      }
    #pragma unroll
    for (int m_=1; m_<16; m_<<=1){
      #pragma unroll
      for (int r=0;r<4;++r) sm[r] += __shfl_xor(sm[r], m_);
    }
    f32x4 oa0 = {0.f,0.f,0.f,0.f}, oa1 = {0.f,0.f,0.f,0.f};
    ushort* pb = Pb[w];
    #pragma unroll
    for (int kc=0; kc<8; ++kc){
      #pragma unroll
      for (int t2=0;t2<2;++t2)
        #pragma unroll
        for (int r=0;r<4;++r)
          pb[(lg*4+r)*40 + t2*16 + lr] = f2bf(sfr[kc*2+t2][r]);
      short8v pf = *(const short8v*)(&pb[lr*40 + lg*8]);
      short8v v0 = *(const short8v*)(&Vt[lr*264 + kc*32 + lg*8]);
      short8v v1 = *(const short8v*)(&Vt[(16+lr)*264 + kc*32 + lg*8]);
      oa0 = __builtin_amdgcn_mfma_f32_16x16x32_bf16(pf, v0, oa0, 0, 0, 0);
      oa1 = __builtin_amdgcn_mfma_f32_16x16x32_bf16(pf, v1, oa1, 0, 0, 0);
    }
    #pragma unroll
    for (int r=0;r<4;++r){
      float inv = 1.0f / sm[r];
      size_t obase = ((size_t)(wi*256 + q0 + lg*4 + r))*256 + h*32;
      Ob[obase + lr]      = f2bf(oa0[r] * inv);
      Ob[obase + 16 + lr] = f2bf(oa1[r] * inv);
    }
  }
}

__global__ void k_zero(const int* __restrict__ desc, float* __restrict__ sums,
                       float* __restrict__ cnts){
  int wi = blockIdx.x;
  int4 d = ((const int4*)desc)[wi];
  if (!d.z) return;
  int b = wi >> 6;
  int t = threadIdx.x;
  int pix = (b*256 + d.x + (t>>4))*256 + d.y + (t&15);
  float4* p = (float4*)(sums + (size_t)pix*256);
  #pragma unroll 8
  for (int c=0;c<64;++c) p[c] = make_float4(0.f,0.f,0.f,0.f);
  atomicAdd(&cnts[pix], 1.0f);
}

// out-proj bf16 MFMA + delta + atomic scatter; x_before read fp32 (XBf)
__global__ __launch_bounds__(256) void k_oproj(const ushort* __restrict__ Ob,
    const ushort* __restrict__ Wq2, const float* __restrict__ out_b,
    const float* __restrict__ XBf, const int* __restrict__ desc,
    float* __restrict__ sums){
  int wi = blockIdx.x;
  int4 dsc = ((const int4*)desc)[wi];
  if (!dsc.z) return;
  int t0 = blockIdx.y * 32;
  __shared__ __align__(16) ushort Os[32*264];
  int tid = threadIdx.x;
  for (int i = tid; i < 1024; i += 256){
    int row = i >> 5, k8 = (i & 31) * 8;
    uint4 vv = *(const uint4*)(Ob + (size_t)(wi*256 + t0 + row)*256 + k8);
    *(uint4*)(&Os[row*264 + k8]) = vv;
  }
  __syncthreads();
  int w = tid >> 6, l = tid & 63;
  int lr = l & 15, lg = l >> 4;
  f32x4 acc[2][4];
  #pragma unroll
  for (int a=0;a<2;++a)
    #pragma unroll
    for (int j=0;j<4;++j) acc[a][j] = (f32x4){0.f,0.f,0.f,0.f};
  for (int kc = 0; kc < 8; ++kc){
    short8v of0 = *(const short8v*)(&Os[lr*264       + kc*32 + lg*8]);
    short8v of1 = *(const short8v*)(&Os[(16+lr)*264 + kc*32 + lg*8]);
    #pragma unroll
    for (int jt = 0; jt < 4; ++jt){
      short8v wf = *(const short8v*)(Wq2 + ((size_t)((w*4 + jt)*8 + kc)*64 + l)*8);
      acc[0][jt] = __builtin_amdgcn_mfma_f32_16x16x32_bf16(of0, wf, acc[0][jt], 0, 0, 0);
      acc[1][jt] = __builtin_amdgcn_mfma_f32_16x16x32_bf16(of1, wf, acc[1][jt], 0, 0, 0);
    }
  }
  int b = wi >> 6;
  #pragma unroll
  for (int ts=0; ts<2; ++ts)
    #pragma unroll
    for (int jt=0; jt<4; ++jt){
      int j = w*64 + jt*16 + lr;
      #pragma unroll
      for (int r=0; r<4; ++r){
        int t = t0 + ts*16 + lg*4 + r;
        int pix = (b*256 + dsc.x + (t>>4))*256 + dsc.y + (t&15);
        float delta = acc[ts][jt][r] + out_b[j] - XBf[((size_t)(wi*256 + t))*256 + j];
        atomicAdd(&sums[(size_t)pix*256 + j], delta);
      }
    }
}

// final depthwise 3x3 over (x + mean): block = (16-col tile, 2-row group, batch)
__global__ __launch_bounds__(256) void k_final(const float* __restrict__ x,
    const float* __restrict__ sums, const float* __restrict__ cnts,
    const float* __restrict__ ocw, const float* __restrict__ ocb,
    float* __restrict__ out){
  int x0 = blockIdx.x * 16;
  int y0 = blockIdx.y * 2;
  int b  = blockIdx.z;
  int c  = threadIdx.x;
  __shared__ float wl[2304];
  __shared__ float bl[256];
  __shared__ float invc[72];
  __shared__ int   anyc;
  if (threadIdx.x == 0) anyc = 0;
  for (int i = threadIdx.x; i < 2304; i += 256) wl[i] = ocw[i];
  bl[c] = ocb[c];
  __syncthreads();
  if (threadIdx.x < 72){
    int rr = threadIdx.x / 18, cc = threadIdx.x % 18;
    int yy = y0 + rr - 1, xx = x0 + cc - 1;
    float iv = 0.f;
    if ((unsigned)yy < 256u && (unsigned)xx < 256u){
      float cv = cnts[(b*256+yy)*256 + xx];
      if (cv > 0.f) iv = 1.0f / cv;
    }
    invc[threadIdx.x] = iv;
    if (iv != 0.f) anyc = 1;
  }
  float v[4][18];
  #pragma unroll
  for (int rr=0; rr<4; ++rr){
    int yy = y0 + rr - 1;
    int yc = min(max(yy, 0), 255);
    float ym = ((unsigned)yy < 256u) ? 1.f : 0.f;
    const float* rowb = x + ((size_t)((b*256+yc)*256))*256 + c;
    #pragma unroll
    for (int cc=0; cc<18; ++cc){
      int xx = x0 + cc - 1;
      int xc = min(max(xx, 0), 255);
      float m = ((unsigned)xx < 256u) ? ym : 0.f;
      v[rr][cc] = rowb[(size_t)xc*256] * m;
    }
  }
  #pragma unroll
  for (int rr=0; rr<4; ++rr)
    #pragma unroll
    for (int cc=0; cc<18; ++cc)
      asm volatile("" : "+v"(v[rr][cc]));
  __syncthreads();
  if (anyc){
    #pragma unroll
    for (int rr=0; rr<4; ++rr){
      int yy = y0 + rr - 1;
      int yc = min(max(yy, 0), 255);
      #pragma unroll
      for (int cc=0; cc<18; ++cc){
        int xx = x0 + cc - 1;
        int xc = min(max(xx, 0), 255);
        float iv = invc[rr*18 + cc];
        const float* bp = (iv != 0.f) ? sums : x;
        size_t idx = ((size_t)((b*256+yc)*256 + xc))*256 + c;
        v[rr][cc] += bp[idx] * iv;
      }
    }
  }
  float w0=wl[c*9+0], w1=wl[c*9+1], w2=wl[c*9+2],
        w3=wl[c*9+3], w4=wl[c*9+4], w5=wl[c*9+5],
        w6=wl[c*9+6], w7=wl[c*9+7], w8=wl[c*9+8];
  float bias = bl[c];
  #pragma unroll
  for (int r=0; r<2; ++r){
    size_t obase = ((size_t)((b*256+y0+r)*256 + x0))*256 + c;
    #pragma unroll
    for (int oc=0; oc<16; ++oc){
      float acc = bias
        + w0*v[r  ][oc] + w1*v[r  ][oc+1] + w2*v[r  ][oc+2]
        + w3*v[r+1][oc] + w4*v[r+1][oc+1] + w5*v[r+1][oc+2]
        + w6*v[r+2][oc] + w7*v[r+2][oc+1] + w8*v[r+2][oc+2];
      out[obase + (size_t)oc*256] = acc;
    }
  }
}

extern "C" void kernel_launch(void* const* d_in, const int* in_sizes, int n_in,
                              void* d_out, int out_size, void* d_ws, size_t ws_size,
                              hipStream_t stream){
  const float* x     = (const float*)d_in[0];
  const float* sd_w1 = (const float*)d_in[1];
  const float* sd_b1 = (const float*)d_in[2];
  const float* sd_w2 = (const float*)d_in[3];
  const float* sd_b2 = (const float*)d_in[4];
  const float* sd_w3 = (const float*)d_in[5];
  const float* sd_b3 = (const float*)d_in[6];
  const float* in_w  = (const float*)d_in[7];
  const float* in_b  = (const float*)d_in[8];
  const float* pe_t  = (const float*)d_in[9];
  const float* out_w = (const float*)d_in[10];
  const float* out_b = (const float*)d_in[11];
  const float* oc_w  = (const float*)d_in[12];
  const float* oc_b  = (const float*)d_in[13];
  float* out = (float*)d_out;
  char* ws = (char*)d_ws;
  if (ws_size < 204003328ULL) return;

  float*  w36 = (float*)(ws + 0);
  float*  t1  = (float*)(ws + 36864);
  float*  t2  = (float*)(ws + 2134016);
  float*  sd3 = (float*)(ws + 2142208);
  int*    desc= (int*)  (ws + 2150400);
  ushort* Wq  = (ushort*)(ws + 2152448);
  ushort* Wq2 = (ushort*)(ws + 2545664);
  float*  XBf = (float*)(ws + 2676736);     // fp32 x_before (written by fused k_qkv)
  float*  p36a= (float*)(ws + 2676736);     // aliases XBf (dead before k_qkv)
  float*  p36b= (float*)(ws + 21551104);    // aliases XBf tail + Ob head
  ushort* Ob  = (ushort*)(ws + 36231168);
  float*  sums= (float*)(ws + 69261312);
  ushort* Qs  = (ushort*)(ws + 69261312);   // aliases sums (dead before k_zero)
  ushort* Kb  = (ushort*)(ws + 86038528);
  ushort* Vb  = (ushort*)(ws + 102815744);
  float*  PEf = (float*)(ws + 119592960);
  float*  cnts= (float*)(ws + 203479040);

  k_w36  <<<36,   256, 0, stream>>>(sd_w1, w36);
  k_wq   <<<96,   256, 0, stream>>>(in_w,  Wq,  24576);
  k_wq   <<<32,   256, 0, stream>>>(out_w, Wq2, 8192);
  k_c1a  <<<dim3(512,2), 256, 0, stream>>>(x, w36, p36a, p36b);
  k_c1b  <<<512,  256, 0, stream>>>(p36a, p36b, sd_b1, t1);
  k_conv2<<<2048, 256, 0, stream>>>(t1, sd_w2, sd_b2, t2);
  k_conv3<<<8,    256, 0, stream>>>(t2, sd_w3, sd_b3, sd3);
  k_topk <<<2,    256, 0, stream>>>(sd3, desc);
  k_pe   <<<2048, 256, 0, stream>>>(pe_t, PEf);
  k_qkv  <<<dim3(128,8),  256, 0, stream>>>(x, Wq, in_b, desc, Qs, Kb, Vb, XBf);
  k_attn <<<dim3(128,8),  256, 0, stream>>>(Qs, Kb, Vb, PEf, desc, Ob);
  hipMemsetAsync(cnts, 0, 524288, stream);
  k_zero <<<128,  256, 0, stream>>>(desc, sums, cnts);
  k_oproj<<<dim3(128,8),  256, 0, stream>>>(Ob, Wq2, out_b, XBf, desc, sums);
  k_final<<<dim3(16,128,2),256, 0, stream>>>(x, sums, cnts, oc_w, oc_b, out);
}

// Round 13
// 272.674 us; speedup vs baseline: 1.0608x; 1.0608x over previous
//
#include <hip/hip_runtime.h>

typedef __attribute__((ext_vector_type(8))) short short8v;
typedef __attribute__((ext_vector_type(4))) float f32x4;

#define DEV __device__ __forceinline__

DEV float sigmoidf_(float x){ return 1.0f/(1.0f+expf(-x)); }
DEV float siluf_(float x){ return x/(1.0f+expf(-x)); }
DEV ushort f2bf(float f){
  union{float f; unsigned u;} a; a.f = f;
  unsigned r = a.u + 0x7fffu + ((a.u >> 16) & 1u);   // RNE
  return (ushort)(r >> 16);
}

// ---------------------------------------------------------------------------
// ws layout (bytes)
//   w36   : 0          36864
//   t1    : 36864      2097152
//   t2    : 2134016    8192
//   sd3   : 2142208    8192
//   desc  : 2150400    2048
//   Wq    : 2152448    393216
//   Wq2   : 2545664    131072
//   XBf   : 2676736    33554432   x_before f32 (128,256,256) [k_xb -> k_oproj]
//     p36a: 2676736    18874368   (aliases XBf head; dead before k_xb)
//     p36b: 21551104   18874368   (aliases XBf tail + Ob head; dead before k_xb)
//   Ob    : 36231168   16777216
//   sums  : 69261312   134217728  -- alive only after k_zero; before that:
//     Qs  : 69261312   16777216   bf16
//     Kb  : 86038528   16777216   bf16 (128,8,256,32)
//     Vb  : 102815744  16777216   bf16 (128,8,256,32)
//     PEf : 119592960  2097152    f32  (8,256,256)
//     XBh : 121690112  16777216   bf16 x_before [k_xb -> k_qkv staging]
//   cnts  : 203479040  524288
// ---------------------------------------------------------------------------

__global__ void k_w36(const float* __restrict__ w1, float* __restrict__ w36){
  int i = blockIdx.x*256 + threadIdx.x;
  if (i < 9216){
    int kk = i % 9, o = (i/9) & 3, c = i / 36;
    w36[i] = w1[(o*256 + c)*9 + kk];
  }
}

// conv1 stage 1, K-split x2 (proven R8 structure)
__global__ __launch_bounds__(256) void k_c1a(const float* __restrict__ x,
    const float* __restrict__ w36, float* __restrict__ p36a, float* __restrict__ p36b){
  int pix = blockIdx.x*256 + threadIdx.x;
  int kb  = blockIdx.y;                       // wave-uniform channel half
  const float* xr = x + (size_t)pix*256 + kb*128;
  const float* wb = w36 + kb*128*36;
  float acc[36];
  #pragma unroll
  for (int j=0;j<36;++j) acc[j]=0.f;
  #pragma unroll 4
  for (int c4=0; c4<32; ++c4){
    float4 xv = *(const float4*)(xr + c4*4);
    float xs[4] = {xv.x, xv.y, xv.z, xv.w};
    #pragma unroll
    for (int e=0;e<4;++e){
      const float4* wrow = (const float4*)(wb + (size_t)(c4*4+e)*36);
      float xe = xs[e];
      #pragma unroll
      for (int jv=0;jv<9;++jv){
        float4 wv = wrow[jv];
        acc[jv*4+0] += xe*wv.x; acc[jv*4+1] += xe*wv.y;
        acc[jv*4+2] += xe*wv.z; acc[jv*4+3] += xe*wv.w;
      }
    }
  }
  float* dst = kb ? p36b : p36a;
  #pragma unroll
  for (int j=0;j<36;++j)
    dst[(size_t)j*131072 + pix] = acc[j];
}

// conv1 stage 2
__global__ __launch_bounds__(256) void k_c1b(const float* __restrict__ p36a,
    const float* __restrict__ p36b, const float* __restrict__ b1,
    float* __restrict__ t1){
  int pix = blockIdx.x*256 + threadIdx.x;     // 131072
  int xp = pix & 255, y = (pix>>8)&255, b = pix>>16;
  float a[4] = {b1[0], b1[1], b1[2], b1[3]};
  #pragma unroll
  for (int ky=0;ky<3;++ky){
    int yy = y+ky-1; if ((unsigned)yy>=256u) continue;
    #pragma unroll
    for (int kx=0;kx<3;++kx){
      int xx = xp+kx-1; if ((unsigned)xx>=256u) continue;
      int np = (b<<16) + yy*256 + xx;
      #pragma unroll
      for (int o=0;o<4;++o){
        size_t idx = (size_t)(o*9+ky*3+kx)*131072 + np;
        a[o] += p36a[idx] + p36b[idx];
      }
    }
  }
  int base = b*262144 + y*256 + xp;
  t1[base]        = siluf_(a[0]);
  t1[base+65536]  = siluf_(a[1]);
  t1[base+131072] = siluf_(a[2]);
  t1[base+196608] = siluf_(a[3]);
}

// pre-fragment a [J][256] f32 weight into bf16 MFMA lane order
__global__ void k_wq(const float* __restrict__ w, ushort* __restrict__ Wq, int nfrag){
  int i = blockIdx.x*256 + threadIdx.x;
  if (i >= nfrag) return;
  int l  = i & 63;
  int kc = (i >> 6) & 7;
  int jt = i >> 9;
  int j = jt*16 + (l & 15);
  int k = kc*32 + (l >> 4)*8;
  const float4* src = (const float4*)(w + j*256 + k);
  float4 v0 = src[0], v1 = src[1];
  union{ uint4 q; ushort u[8]; } o;
  o.u[0]=f2bf(v0.x); o.u[1]=f2bf(v0.y); o.u[2]=f2bf(v0.z); o.u[3]=f2bf(v0.w);
  o.u[4]=f2bf(v1.x); o.u[5]=f2bf(v1.y); o.u[6]=f2bf(v1.z); o.u[7]=f2bf(v1.w);
  *(uint4*)(Wq + (size_t)i*8) = o.q;
}

__global__ void k_conv2(const float* __restrict__ t1, const float* __restrict__ w2,
                        const float* __restrict__ b2, float* __restrict__ t2){
  int oidx = blockIdx.x;
  int ox = oidx & 15, oy = (oidx>>4)&15, o = (oidx>>8)&3, b = oidx>>10;
  int t = threadIdx.x;
  float acc = 0.f;
  #pragma unroll
  for (int uu=0; uu<4; ++uu){
    int u = t + uu*256;
    int ic = u >> 8, ky = (u>>4)&15, kx = u&15;
    float xv = t1[(b*4+ic)*65536 + (oy*16+ky)*256 + (ox*16+kx)];
    float wv = w2[(o*4+ic)*256 + ky*16 + kx];
    acc += xv*wv;
  }
  __shared__ float red[256];
  red[t] = acc; __syncthreads();
  for (int s=128; s>0; s>>=1){ if (t<s) red[t]+=red[t+s]; __syncthreads(); }
  if (t==0) t2[oidx] = siluf_(red[0] + b2[o]);
}

__global__ void k_conv3(const float* __restrict__ t2, const float* __restrict__ w3,
                        const float* __restrict__ b3, float* __restrict__ sd3){
  int i = blockIdx.x*256 + threadIdx.x;
  int ox = i & 15, oy = (i>>4)&15, o = (i>>8)&3, b = i>>10;
  float acc = b3[o];
  for (int ic=0; ic<4; ++ic){
    const float* src = t2 + (b*4+ic)*256;
    const float* ww  = w3 + (o*4+ic)*9;
    #pragma unroll
    for (int ky=0; ky<3; ++ky){
      int yy = oy + ky - 1; if ((unsigned)yy >= 16u) continue;
      #pragma unroll
      for (int kx=0; kx<3; ++kx){
        int xx = ox + kx - 1; if ((unsigned)xx >= 16u) continue;
        acc += src[yy*16+xx] * ww[ky*3+kx];
      }
    }
  }
  sd3[i] = acc;
}

__global__ void k_topk(const float* __restrict__ sd3, int* __restrict__ desc){
  int b = blockIdx.x, t = threadIdx.x;
  __shared__ float sc[256];
  sc[t] = sd3[(b*4+0)*256 + t];
  __syncthreads();
  float st = sc[t];
  int rank = 0;
  for (int j=0;j<256;++j){
    float sj = sc[j];
    rank += (sj > st) || (sj == st && j < t);
  }
  if (rank < 64){
    float g = sigmoidf_(sd3[(b*4+1)*256 + t]);
    int hard = (g > 0.5f) ? 1 : 0;
    float offh = sigmoidf_(sd3[(b*4+2)*256 + t]) * 16.0f - 8.0f;
    float offw = sigmoidf_(sd3[(b*4+3)*256 + t]) * 16.0f - 8.0f;
    int hoff = (int)offh, woff = (int)offw;
    int h1 = min(max((t>>4)*16 + hoff, 0), 240);
    int w1 = min(max((t&15)*16 + woff, 0), 240);
    ((int4*)desc)[b*64 + rank] = make_int4(h1, w1, hard, 0);
  }
}

// bilinear gather: one block per (window,row); writes fp32 XBf + bf16 XBh
__global__ __launch_bounds__(256) void k_xb(const float* __restrict__ x,
    const int* __restrict__ desc, float* __restrict__ XBf, ushort* __restrict__ XBh){
  int wi = blockIdx.x;
  int4 d = ((const int4*)desc)[wi];
  if (!d.z) return;
  int b = wi >> 6;
  int ty = blockIdx.y;
  int tid = threadIdx.x;
  int tx = tid >> 4;
  int cl = (tid & 15) * 4;
  float yyf = fminf((float)(d.x + ty) + 0.5f, 255.0f);
  int y0 = (int)yyf; float ly = yyf - (float)y0; int y1 = min(y0+1, 255);
  float xxf = fminf((float)(d.y + tx) + 0.5f, 255.0f);
  int x0 = (int)xxf; float lx = xxf - (float)x0; int x1 = min(x0+1, 255);
  float w00=(1.f-ly)*(1.f-lx), w01=(1.f-ly)*lx, w10=ly*(1.f-lx), w11=ly*lx;
  const float* p00 = x + ((b*256+y0)*256 + x0)*256;
  const float* p01 = x + ((b*256+y0)*256 + x1)*256;
  const float* p10 = x + ((b*256+y1)*256 + x0)*256;
  const float* p11 = x + ((b*256+y1)*256 + x1)*256;
  size_t tokoff = ((size_t)(wi*256 + ty*16 + tx))*256;
  float* dst = XBf + tokoff;
  ushort* dsth = XBh + tokoff;
  #pragma unroll
  for (int u=0; u<4; ++u){
    int c = cl + u*64;
    float4 A = *(const float4*)(p00+c);
    float4 Bv= *(const float4*)(p01+c);
    float4 Cv= *(const float4*)(p10+c);
    float4 Dv= *(const float4*)(p11+c);
    float4 r;
    r.x = w00*A.x + w01*Bv.x + w10*Cv.x + w11*Dv.x;
    r.y = w00*A.y + w01*Bv.y + w10*Cv.y + w11*Dv.y;
    r.z = w00*A.z + w01*Bv.z + w10*Cv.z + w11*Dv.z;
    r.w = w00*A.w + w01*Bv.w + w10*Cv.w + w11*Dv.w;
    *(float4*)(dst + c) = r;
    *(ushort4*)(dsth + c) = make_ushort4(f2bf(r.x), f2bf(r.y), f2bf(r.z), f2bf(r.w));
  }
}

// QKV GEMM, bf16 MFMA. block=(window, 32-row tile); stages bf16 XBh via uint4
__global__ __launch_bounds__(256) void k_qkv(const ushort* __restrict__ XBh,
    const ushort* __restrict__ Wq, const float* __restrict__ in_b,
    const int* __restrict__ desc, ushort* __restrict__ Qs,
    ushort* __restrict__ Kb, ushort* __restrict__ Vb){
  int wi = blockIdx.x;
  if (((const int4*)desc)[wi].z == 0) return;
  int t0 = blockIdx.y * 32;
  __shared__ __align__(16) ushort Xs[32*264];
  int tid = threadIdx.x;
  const ushort* Ab = XBh + (size_t)(wi*256 + t0)*256;
  #pragma unroll
  for (int it = 0; it < 4; ++it){
    int i = tid + it*256;
    int row = i >> 5, k8 = (i & 31) * 8;
    *(uint4*)(&Xs[row*264 + k8]) = *(const uint4*)(Ab + row*256 + k8);
  }
  __syncthreads();
  int w = tid >> 6, l = tid & 63;
  int lr = l & 15, lg = l >> 4;
  f32x4 acc[2][12];
  #pragma unroll
  for (int a=0;a<2;++a)
    #pragma unroll
    for (int j=0;j<12;++j) acc[a][j] = (f32x4){0.f,0.f,0.f,0.f};
  for (int kc = 0; kc < 8; ++kc){
    short8v xf0 = *(const short8v*)(&Xs[lr*264       + kc*32 + lg*8]);
    short8v xf1 = *(const short8v*)(&Xs[(16+lr)*264 + kc*32 + lg*8]);
    #pragma unroll
    for (int jt = 0; jt < 12; ++jt){
      short8v wf = *(const short8v*)(Wq + ((size_t)((w*12 + jt)*8 + kc)*64 + l)*8);
      acc[0][jt] = __builtin_amdgcn_mfma_f32_16x16x32_bf16(xf0, wf, acc[0][jt], 0, 0, 0);
      acc[1][jt] = __builtin_amdgcn_mfma_f32_16x16x32_bf16(xf1, wf, acc[1][jt], 0, 0, 0);
    }
  }
  #pragma unroll
  for (int ts=0; ts<2; ++ts)
    #pragma unroll
    for (int jt=0; jt<12; ++jt){
      int j = w*192 + jt*16 + lr;
      #pragma unroll
      for (int r=0; r<4; ++r){
        int t = t0 + ts*16 + lg*4 + r;
        float val = acc[ts][jt][r] + in_b[j];
        if (j < 256){
          Qs[((size_t)(wi*256 + t))*256 + j] = f2bf(val * 0.17677669529663687f);
        } else if (j < 512){
          int jq = j - 256;
          Kb[((size_t)(wi*8 + (jq>>5))*256 + t)*32 + (jq&31)] = f2bf(val);
        } else {
          int jq = j - 512;
          Vb[((size_t)(wi*8 + (jq>>5))*256 + t)*32 + (jq&31)] = f2bf(val);
        }
      }
    }
}

// PE table expanded to [h][q][j] f32
__global__ void k_pe(const float* __restrict__ pe_table, float* __restrict__ PEf){
  int id = blockIdx.x*256 + threadIdx.x;    // 524288
  int h = id >> 16, q = (id>>8)&255, j = id&255;
  int ih = (q>>4) - (j>>4) + 15;
  int iw = (q&15) - (j&15) + 15;
  PEf[id] = pe_table[(ih*31+iw)*8 + h];
}

// MFMA bf16 attention
__global__ __launch_bounds__(256,2) void k_attn(const ushort* __restrict__ Qs,
    const ushort* __restrict__ Kb, const ushort* __restrict__ Vb,
    const float* __restrict__ PEf, const int* __restrict__ desc,
    ushort* __restrict__ Ob){
  int wi = blockIdx.x, h = blockIdx.y;
  if (((const int4*)desc)[wi].z == 0) return;
  __shared__ __align__(16) ushort Ks[256*40];
  __shared__ __align__(16) ushort Vt[32*264];
  __shared__ __align__(16) ushort Pb[4][16*40];
  int tid = threadIdx.x;
  {
    const uint4* src = (const uint4*)(Kb + (size_t)((wi*8+h)*256 + tid)*32);
    uint4 a = src[0], b = src[1], c = src[2], d = src[3];
    *(uint4*)(&Ks[tid*40 +  0]) = a;
    *(uint4*)(&Ks[tid*40 +  8]) = b;
    *(uint4*)(&Ks[tid*40 + 16]) = c;
    *(uint4*)(&Ks[tid*40 + 24]) = d;
  }
  {
    const uint4* src = (const uint4*)(Vb + (size_t)((wi*8+h)*256 + tid)*32);
    #pragma unroll
    for (int c4=0; c4<4; ++c4){
      union{uint4 v; ushort u[8];} uu; uu.v = src[c4];
      #pragma unroll
      for (int e=0;e<8;++e) Vt[(c4*8+e)*264 + tid] = uu.u[e];
    }
  }
  __syncthreads();
  int w = tid >> 6, l = tid & 63;
  int lg = l >> 4, lr = l & 15;
  const float* PEh = PEf + h*65536;
  for (int s_i = 0; s_i < 4; ++s_i){
    int q0 = (w*4 + s_i)*16;
    short8v qf = *(const short8v*)(Qs + ((size_t)(wi*256 + q0 + lr))*256 + h*32 + lg*8);
    f32x4 sfr[16];
    #pragma unroll
    for (int jt=0; jt<16; ++jt){
      f32x4 c;
      #pragma unroll
      for (int r=0;r<4;++r) c[r] = PEh[(q0 + lg*4 + r)*256 + jt*16 + lr];
      short8v kf = *(const short8v*)(&Ks[(jt*16 + lr)*40 + lg*8]);
      sfr[jt] = __builtin_amdgcn_mfma_f32_16x16x32_bf16(qf, kf, c, 0, 0, 0);
    }
    float mx[4] = {-1e30f,-1e30f,-1e30f,-1e30f};
    #pragma unroll
    for (int jt=0;jt<16;++jt)
      #pragma unroll
      for (int r=0;r<4;++r) mx[r] = fmaxf(mx[r], sfr[jt][r]);
    #pragma unroll
    for (int m_=1; m_<16; m_<<=1){
      #pragma unroll
      for (int r=0;r<4;++r) mx[r] = fmaxf(mx[r], __shfl_xor(mx[r], m_));
    }
    float sm[4] = {0.f,0.f,0.f,0.f};
    #pragma unroll
    for (int jt=0;jt<16;++jt)
      #pragma unroll
      for (int r=0;r<4;++r){
        float p = __expf(sfr[jt][r] - mx[r]);
        sfr[jt][r] = p; sm[r] += p;
      }
    #pragma unroll
    for (int m_=1; m_<16; m_<<=1){
      #pragma unroll
      for (int r=0;r<4;++r) sm[r] += __shfl_xor(sm[r], m_);
    }
    f32x4 oa0 = {0.f,0.f,0.f,0.f}, oa1 = {0.f,0.f,0.f,0.f};
    ushort* pb = Pb[w];
    #pragma unroll
    for (int kc=0; kc<8; ++kc){
      #pragma unroll
      for (int t2=0;t2<2;++t2)
        #pragma unroll
        for (int r=0;r<4;++r)
          pb[(lg*4+r)*40 + t2*16 + lr] = f2bf(sfr[kc*2+t2][r]);
      short8v pf = *(const short8v*)(&pb[lr*40 + lg*8]);
      short8v v0 = *(const short8v*)(&Vt[lr*264 + kc*32 + lg*8]);
      short8v v1 = *(const short8v*)(&Vt[(16+lr)*264 + kc*32 + lg*8]);
      oa0 = __builtin_amdgcn_mfma_f32_16x16x32_bf16(pf, v0, oa0, 0, 0, 0);
      oa1 = __builtin_amdgcn_mfma_f32_16x16x32_bf16(pf, v1, oa1, 0, 0, 0);
    }
    #pragma unroll
    for (int r=0;r<4;++r){
      float inv = 1.0f / sm[r];
      size_t obase = ((size_t)(wi*256 + q0 + lg*4 + r))*256 + h*32;
      Ob[obase + lr]      = f2bf(oa0[r] * inv);
      Ob[obase + 16 + lr] = f2bf(oa1[r] * inv);
    }
  }
}

__global__ void k_zero(const int* __restrict__ desc, float* __restrict__ sums,
                       float* __restrict__ cnts){
  int wi = blockIdx.x;
  int4 d = ((const int4*)desc)[wi];
  if (!d.z) return;
  int b = wi >> 6;
  int t = threadIdx.x;
  int pix = (b*256 + d.x + (t>>4))*256 + d.y + (t&15);
  float4* p = (float4*)(sums + (size_t)pix*256);
  #pragma unroll 8
  for (int c=0;c<64;++c) p[c] = make_float4(0.f,0.f,0.f,0.f);
  atomicAdd(&cnts[pix], 1.0f);
}

// out-proj bf16 MFMA + delta + atomic scatter; x_before read fp32 (XBf)
__global__ __launch_bounds__(256) void k_oproj(const ushort* __restrict__ Ob,
    const ushort* __restrict__ Wq2, const float* __restrict__ out_b,
    const float* __restrict__ XBf, const int* __restrict__ desc,
    float* __restrict__ sums){
  int wi = blockIdx.x;
  int4 dsc = ((const int4*)desc)[wi];
  if (!dsc.z) return;
  int t0 = blockIdx.y * 32;
  __shared__ __align__(16) ushort Os[32*264];
  int tid = threadIdx.x;
  for (int i = tid; i < 1024; i += 256){
    int row = i >> 5, k8 = (i & 31) * 8;
    uint4 vv = *(const uint4*)(Ob + (size_t)(wi*256 + t0 + row)*256 + k8);
    *(uint4*)(&Os[row*264 + k8]) = vv;
  }
  __syncthreads();
  int w = tid >> 6, l = tid & 63;
  int lr = l & 15, lg = l >> 4;
  f32x4 acc[2][4];
  #pragma unroll
  for (int a=0;a<2;++a)
    #pragma unroll
    for (int j=0;j<4;++j) acc[a][j] = (f32x4){0.f,0.f,0.f,0.f};
  for (int kc = 0; kc < 8; ++kc){
    short8v of0 = *(const short8v*)(&Os[lr*264       + kc*32 + lg*8]);
    short8v of1 = *(const short8v*)(&Os[(16+lr)*264 + kc*32 + lg*8]);
    #pragma unroll
    for (int jt = 0; jt < 4; ++jt){
      short8v wf = *(const short8v*)(Wq2 + ((size_t)((w*4 + jt)*8 + kc)*64 + l)*8);
      acc[0][jt] = __builtin_amdgcn_mfma_f32_16x16x32_bf16(of0, wf, acc[0][jt], 0, 0, 0);
      acc[1][jt] = __builtin_amdgcn_mfma_f32_16x16x32_bf16(of1, wf, acc[1][jt], 0, 0, 0);
    }
  }
  int b = wi >> 6;
  #pragma unroll
  for (int ts=0; ts<2; ++ts)
    #pragma unroll
    for (int jt=0; jt<4; ++jt){
      int j = w*64 + jt*16 + lr;
      #pragma unroll
      for (int r=0; r<4; ++r){
        int t = t0 + ts*16 + lg*4 + r;
        int pix = (b*256 + dsc.x + (t>>4))*256 + dsc.y + (t&15);
        float delta = acc[ts][jt][r] + out_b[j] - XBf[((size_t)(wi*256 + t))*256 + j];
        atomicAdd(&sums[(size_t)pix*256 + j], delta);
      }
    }
}

// final depthwise 3x3 over (x + mean): block = (16-col tile, 2-row group, batch)
__global__ __launch_bounds__(256) void k_final(const float* __restrict__ x,
    const float* __restrict__ sums, const float* __restrict__ cnts,
    const float* __restrict__ ocw, const float* __restrict__ ocb,
    float* __restrict__ out){
  int x0 = blockIdx.x * 16;
  int y0 = blockIdx.y * 2;
  int b  = blockIdx.z;
  int c  = threadIdx.x;
  __shared__ float wl[2304];
  __shared__ float bl[256];
  __shared__ float invc[72];
  __shared__ int   anyc;
  if (threadIdx.x == 0) anyc = 0;
  for (int i = threadIdx.x; i < 2304; i += 256) wl[i] = ocw[i];
  bl[c] = ocb[c];
  __syncthreads();
  if (threadIdx.x < 72){
    int rr = threadIdx.x / 18, cc = threadIdx.x % 18;
    int yy = y0 + rr - 1, xx = x0 + cc - 1;
    float iv = 0.f;
    if ((unsigned)yy < 256u && (unsigned)xx < 256u){
      float cv = cnts[(b*256+yy)*256 + xx];
      if (cv > 0.f) iv = 1.0f / cv;
    }
    invc[threadIdx.x] = iv;
    if (iv != 0.f) anyc = 1;
  }
  float v[4][18];
  #pragma unroll
  for (int rr=0; rr<4; ++rr){
    int yy = y0 + rr - 1;
    int yc = min(max(yy, 0), 255);
    float ym = ((unsigned)yy < 256u) ? 1.f : 0.f;
    const float* rowb = x + ((size_t)((b*256+yc)*256))*256 + c;
    #pragma unroll
    for (int cc=0; cc<18; ++cc){
      int xx = x0 + cc - 1;
      int xc = min(max(xx, 0), 255);
      float m = ((unsigned)xx < 256u) ? ym : 0.f;
      v[rr][cc] = rowb[(size_t)xc*256] * m;
    }
  }
  #pragma unroll
  for (int rr=0; rr<4; ++rr)
    #pragma unroll
    for (int cc=0; cc<18; ++cc)
      asm volatile("" : "+v"(v[rr][cc]));
  __syncthreads();
  if (anyc){
    #pragma unroll
    for (int rr=0; rr<4; ++rr){
      int yy = y0 + rr - 1;
      int yc = min(max(yy, 0), 255);
      #pragma unroll
      for (int cc=0; cc<18; ++cc){
        int xx = x0 + cc - 1;
        int xc = min(max(xx, 0), 255);
        float iv = invc[rr*18 + cc];
        const float* bp = (iv != 0.f) ? sums : x;
        size_t idx = ((size_t)((b*256+yc)*256 + xc))*256 + c;
        v[rr][cc] += bp[idx] * iv;
      }
    }
  }
  float w0=wl[c*9+0], w1=wl[c*9+1], w2=wl[c*9+2],
        w3=wl[c*9+3], w4=wl[c*9+4], w5=wl[c*9+5],
        w6=wl[c*9+6], w7=wl[c*9+7], w8=wl[c*9+8];
  float bias = bl[c];
  #pragma unroll
  for (int r=0; r<2; ++r){
    size_t obase = ((size_t)((b*256+y0+r)*256 + x0))*256 + c;
    #pragma unroll
    for (int oc=0; oc<16; ++oc){
      float acc = bias
        + w0*v[r  ][oc] + w1*v[r  ][oc+1] + w2*v[r  ][oc+2]
        + w3*v[r+1][oc] + w4*v[r+1][oc+1] + w5*v[r+1][oc+2]
        + w6*v[r+2][oc] + w7*v[r+2][oc+1] + w8*v[r+2][oc+2];
      out[obase + (size_t)oc*256] = acc;
    }
  }
}

extern "C" void kernel_launch(void* const* d_in, const int* in_sizes, int n_in,
                              void* d_out, int out_size, void* d_ws, size_t ws_size,
                              hipStream_t stream){
  const float* x     = (const float*)d_in[0];
  const float* sd_w1 = (const float*)d_in[1];
  const float* sd_b1 = (const float*)d_in[2];
  const float* sd_w2 = (const float*)d_in[3];
  const float* sd_b2 = (const float*)d_in[4];
  const float* sd_w3 = (const float*)d_in[5];
  const float* sd_b3 = (const float*)d_in[6];
  const float* in_w  = (const float*)d_in[7];
  const float* in_b  = (const float*)d_in[8];
  const float* pe_t  = (const float*)d_in[9];
  const float* out_w = (const float*)d_in[10];
  const float* out_b = (const float*)d_in[11];
  const float* oc_w  = (const float*)d_in[12];
  const float* oc_b  = (const float*)d_in[13];
  float* out = (float*)d_out;
  char* ws = (char*)d_ws;
  if (ws_size < 204003328ULL) return;

  float*  w36 = (float*)(ws + 0);
  float*  t1  = (float*)(ws + 36864);
  float*  t2  = (float*)(ws + 2134016);
  float*  sd3 = (float*)(ws + 2142208);
  int*    desc= (int*)  (ws + 2150400);
  ushort* Wq  = (ushort*)(ws + 2152448);
  ushort* Wq2 = (ushort*)(ws + 2545664);
  float*  XBf = (float*)(ws + 2676736);     // fp32 x_before
  float*  p36a= (float*)(ws + 2676736);     // aliases XBf (dead before k_xb)
  float*  p36b= (float*)(ws + 21551104);    // aliases XBf tail + Ob head
  ushort* Ob  = (ushort*)(ws + 36231168);
  float*  sums= (float*)(ws + 69261312);
  ushort* Qs  = (ushort*)(ws + 69261312);   // aliases sums (dead before k_zero)
  ushort* Kb  = (ushort*)(ws + 86038528);
  ushort* Vb  = (ushort*)(ws + 102815744);
  float*  PEf = (float*)(ws + 119592960);
  ushort* XBh = (ushort*)(ws + 121690112);  // bf16 x_before (dead before k_zero)
  float*  cnts= (float*)(ws + 203479040);

  k_w36  <<<36,   256, 0, stream>>>(sd_w1, w36);
  k_wq   <<<96,   256, 0, stream>>>(in_w,  Wq,  24576);
  k_wq   <<<32,   256, 0, stream>>>(out_w, Wq2, 8192);
  k_c1a  <<<dim3(512,2), 256, 0, stream>>>(x, w36, p36a, p36b);
  k_c1b  <<<512,  256, 0, stream>>>(p36a, p36b, sd_b1, t1);
  k_conv2<<<2048, 256, 0, stream>>>(t1, sd_w2, sd_b2, t2);
  k_conv3<<<8,    256, 0, stream>>>(t2, sd_w3, sd_b3, sd3);
  k_topk <<<2,    256, 0, stream>>>(sd3, desc);
  k_pe   <<<2048, 256, 0, stream>>>(pe_t, PEf);
  k_xb   <<<dim3(128,16), 256, 0, stream>>>(x, desc, XBf, XBh);
  k_qkv  <<<dim3(128,8),  256, 0, stream>>>(XBh, Wq, in_b, desc, Qs, Kb, Vb);
  k_attn <<<dim3(128,8),  256, 0, stream>>>(Qs, Kb, Vb, PEf, desc, Ob);
  hipMemsetAsync(cnts, 0, 524288, stream);
  k_zero <<<128,  256, 0, stream>>>(desc, sums, cnts);
  k_oproj<<<dim3(128,8),  256, 0, stream>>>(Ob, Wq2, out_b, XBf, desc, sums);
  k_final<<<dim3(16,128,2),256, 0, stream>>>(x, sums, cnts, oc_w, oc_b, out);
}

// Round 14
// 267.329 us; speedup vs baseline: 1.0820x; 1.0200x over previous
//
#include <hip/hip_runtime.h>

typedef __attribute__((ext_vector_type(8))) short short8v;
typedef __attribute__((ext_vector_type(4))) float f32x4;

#define DEV __device__ __forceinline__

DEV float sigmoidf_(float x){ return 1.0f/(1.0f+expf(-x)); }
DEV float siluf_(float x){ return x/(1.0f+expf(-x)); }
DEV ushort f2bf(float f){
  union{float f; unsigned u;} a; a.f = f;
  unsigned r = a.u + 0x7fffu + ((a.u >> 16) & 1u);   // RNE
  return (ushort)(r >> 16);
}

// ---------------------------------------------------------------------------
// ws layout (bytes)
//   w36   : 0          36864
//   t1    : 36864      2097152
//   t2    : 2134016    8192
//   desc  : 2150400    2048
//   Wq    : 2152448    393216
//   Wq2   : 2545664    131072
//   XBf   : 2676736    33554432   x_before f32 [k_xb -> k_oproj]
//     p36a: 2676736    18874368   (aliases XBf head; dead before k_xb)
//     p36b: 21551104   18874368   (aliases XBf tail + Ob head; dead before k_xb)
//   Ob    : 36231168   16777216
//   sums  : 69261312   134217728  -- alive only after k_zero; before that:
//     Qs  : 69261312   16777216
//     Kb  : 86038528   16777216
//     Vb  : 102815744  16777216
//     PEf : 119592960  2097152
//     XBh : 121690112  16777216   bf16 x_before [k_xb -> k_qkv staging]
//   cnts  : 203479040  524288
// ---------------------------------------------------------------------------

DEV void wq_frag(const float* __restrict__ w, ushort* __restrict__ Wq,
                 int i, int nfrag){
  if (i >= nfrag) return;
  int l  = i & 63;
  int kc = (i >> 6) & 7;
  int jt = i >> 9;
  int j = jt*16 + (l & 15);
  int k = kc*32 + (l >> 4)*8;
  const float4* src = (const float4*)(w + j*256 + k);
  float4 v0 = src[0], v1 = src[1];
  union{ uint4 q; ushort u[8]; } o;
  o.u[0]=f2bf(v0.x); o.u[1]=f2bf(v0.y); o.u[2]=f2bf(v0.z); o.u[3]=f2bf(v0.w);
  o.u[4]=f2bf(v1.x); o.u[5]=f2bf(v1.y); o.u[6]=f2bf(v1.z); o.u[7]=f2bf(v1.w);
  *(uint4*)(Wq + (size_t)i*8) = o.q;
}

// fused prep: PEf expand | w36 reorder | Wq frag | Wq2 frag | cnts zero
__global__ void k_prep(const float* __restrict__ w1, float* __restrict__ w36,
                       const float* __restrict__ in_w, ushort* __restrict__ Wq,
                       const float* __restrict__ out_w, ushort* __restrict__ Wq2,
                       const float* __restrict__ pe_table, float* __restrict__ PEf,
                       float* __restrict__ cnts){
  int bid = blockIdx.x, t = threadIdx.x;
  if (bid < 2048){
    int id = bid*256 + t;
    int h = id >> 16, q = (id>>8)&255, j = id&255;
    int ih = (q>>4) - (j>>4) + 15;
    int iw = (q&15) - (j&15) + 15;
    PEf[id] = pe_table[(ih*31+iw)*8 + h];
  } else if (bid < 2084){
    int i = (bid-2048)*256 + t;
    if (i < 9216){
      int kk = i % 9, o = (i/9) & 3, c = i / 36;
      w36[i] = w1[(o*256 + c)*9 + kk];
    }
  } else if (bid < 2180){
    wq_frag(in_w, Wq, (bid-2084)*256 + t, 24576);
  } else if (bid < 2212){
    wq_frag(out_w, Wq2, (bid-2180)*256 + t, 8192);
  } else {
    int i = (bid-2212)*256 + t;     // 16384 threads x 2 float4 = 131072 floats
    float4 z = make_float4(0.f,0.f,0.f,0.f);
    ((float4*)cnts)[i*2]   = z;
    ((float4*)cnts)[i*2+1] = z;
  }
}

// conv1 stage 1, K-split x2 (proven R8 structure)
__global__ __launch_bounds__(256) void k_c1a(const float* __restrict__ x,
    const float* __restrict__ w36, float* __restrict__ p36a, float* __restrict__ p36b){
  int pix = blockIdx.x*256 + threadIdx.x;
  int kb  = blockIdx.y;                       // wave-uniform channel half
  const float* xr = x + (size_t)pix*256 + kb*128;
  const float* wb = w36 + kb*128*36;
  float acc[36];
  #pragma unroll
  for (int j=0;j<36;++j) acc[j]=0.f;
  #pragma unroll 4
  for (int c4=0; c4<32; ++c4){
    float4 xv = *(const float4*)(xr + c4*4);
    float xs[4] = {xv.x, xv.y, xv.z, xv.w};
    #pragma unroll
    for (int e=0;e<4;++e){
      const float4* wrow = (const float4*)(wb + (size_t)(c4*4+e)*36);
      float xe = xs[e];
      #pragma unroll
      for (int jv=0;jv<9;++jv){
        float4 wv = wrow[jv];
        acc[jv*4+0] += xe*wv.x; acc[jv*4+1] += xe*wv.y;
        acc[jv*4+2] += xe*wv.z; acc[jv*4+3] += xe*wv.w;
      }
    }
  }
  float* dst = kb ? p36b : p36a;
  #pragma unroll
  for (int j=0;j<36;++j)
    dst[(size_t)j*131072 + pix] = acc[j];
}

// conv1 stage 2
__global__ __launch_bounds__(256) void k_c1b(const float* __restrict__ p36a,
    const float* __restrict__ p36b, const float* __restrict__ b1,
    float* __restrict__ t1){
  int pix = blockIdx.x*256 + threadIdx.x;     // 131072
  int xp = pix & 255, y = (pix>>8)&255, b = pix>>16;
  float a[4] = {b1[0], b1[1], b1[2], b1[3]};
  #pragma unroll
  for (int ky=0;ky<3;++ky){
    int yy = y+ky-1; if ((unsigned)yy>=256u) continue;
    #pragma unroll
    for (int kx=0;kx<3;++kx){
      int xx = xp+kx-1; if ((unsigned)xx>=256u) continue;
      int np = (b<<16) + yy*256 + xx;
      #pragma unroll
      for (int o=0;o<4;++o){
        size_t idx = (size_t)(o*9+ky*3+kx)*131072 + np;
        a[o] += p36a[idx] + p36b[idx];
      }
    }
  }
  int base = b*262144 + y*256 + xp;
  t1[base]        = siluf_(a[0]);
  t1[base+65536]  = siluf_(a[1]);
  t1[base+131072] = siluf_(a[2]);
  t1[base+196608] = siluf_(a[3]);
}

__global__ void k_conv2(const float* __restrict__ t1, const float* __restrict__ w2,
                        const float* __restrict__ b2, float* __restrict__ t2){
  int oidx = blockIdx.x;
  int ox = oidx & 15, oy = (oidx>>4)&15, o = (oidx>>8)&3, b = oidx>>10;
  int t = threadIdx.x;
  float acc = 0.f;
  #pragma unroll
  for (int uu=0; uu<4; ++uu){
    int u = t + uu*256;
    int ic = u >> 8, ky = (u>>4)&15, kx = u&15;
    float xv = t1[(b*4+ic)*65536 + (oy*16+ky)*256 + (ox*16+kx)];
    float wv = w2[(o*4+ic)*256 + ky*16 + kx];
    acc += xv*wv;
  }
  __shared__ float red[256];
  red[t] = acc; __syncthreads();
  for (int s=128; s>0; s>>=1){ if (t<s) red[t]+=red[t+s]; __syncthreads(); }
  if (t==0) t2[oidx] = siluf_(red[0] + b2[o]);
}

// fused conv3 + topk: one block per batch; sd3 lives in LDS only
__global__ void k_sel(const float* __restrict__ t2, const float* __restrict__ w3,
                      const float* __restrict__ b3, int* __restrict__ desc){
  int b = blockIdx.x, t = threadIdx.x;
  __shared__ float sd[1024];
  #pragma unroll
  for (int oo=0; oo<4; ++oo){
    int idx = t + oo*256;
    int o = idx >> 8, oy = (idx>>4)&15, ox = idx&15;
    float acc = b3[o];
    for (int ic=0; ic<4; ++ic){
      const float* src = t2 + (b*4+ic)*256;
      const float* ww  = w3 + (o*4+ic)*9;
      #pragma unroll
      for (int ky=0; ky<3; ++ky){
        int yy = oy + ky - 1; if ((unsigned)yy >= 16u) continue;
        #pragma unroll
        for (int kx=0; kx<3; ++kx){
          int xx = ox + kx - 1; if ((unsigned)xx >= 16u) continue;
          acc += src[yy*16+xx] * ww[ky*3+kx];
        }
      }
    }
    sd[idx] = acc;
  }
  __syncthreads();
  float st = sd[t];
  int rank = 0;
  for (int j=0;j<256;++j){
    float sj = sd[j];
    rank += (sj > st) || (sj == st && j < t);
  }
  if (rank < 64){
    float g = sigmoidf_(sd[256 + t]);
    int hard = (g > 0.5f) ? 1 : 0;
    float offh = sigmoidf_(sd[512 + t]) * 16.0f - 8.0f;
    float offw = sigmoidf_(sd[768 + t]) * 16.0f - 8.0f;
    int hoff = (int)offh, woff = (int)offw;
    int h1 = min(max((t>>4)*16 + hoff, 0), 240);
    int w1 = min(max((t&15)*16 + woff, 0), 240);
    ((int4*)desc)[b*64 + rank] = make_int4(h1, w1, hard, 0);
  }
}

// bilinear gather: one block per (window,row); writes fp32 XBf + bf16 XBh
__global__ __launch_bounds__(256) void k_xb(const float* __restrict__ x,
    const int* __restrict__ desc, float* __restrict__ XBf, ushort* __restrict__ XBh){
  int wi = blockIdx.x;
  int4 d = ((const int4*)desc)[wi];
  if (!d.z) return;
  int b = wi >> 6;
  int ty = blockIdx.y;
  int tid = threadIdx.x;
  int tx = tid >> 4;
  int cl = (tid & 15) * 4;
  float yyf = fminf((float)(d.x + ty) + 0.5f, 255.0f);
  int y0 = (int)yyf; float ly = yyf - (float)y0; int y1 = min(y0+1, 255);
  float xxf = fminf((float)(d.y + tx) + 0.5f, 255.0f);
  int x0 = (int)xxf; float lx = xxf - (float)x0; int x1 = min(x0+1, 255);
  float w00=(1.f-ly)*(1.f-lx), w01=(1.f-ly)*lx, w10=ly*(1.f-lx), w11=ly*lx;
  const float* p00 = x + ((b*256+y0)*256 + x0)*256;
  const float* p01 = x + ((b*256+y0)*256 + x1)*256;
  const float* p10 = x + ((b*256+y1)*256 + x0)*256;
  const float* p11 = x + ((b*256+y1)*256 + x1)*256;
  size_t tokoff = ((size_t)(wi*256 + ty*16 + tx))*256;
  float* dst = XBf + tokoff;
  ushort* dsth = XBh + tokoff;
  #pragma unroll
  for (int u=0; u<4; ++u){
    int c = cl + u*64;
    float4 A = *(const float4*)(p00+c);
    float4 Bv= *(const float4*)(p01+c);
    float4 Cv= *(const float4*)(p10+c);
    float4 Dv= *(const float4*)(p11+c);
    float4 r;
    r.x = w00*A.x + w01*Bv.x + w10*Cv.x + w11*Dv.x;
    r.y = w00*A.y + w01*Bv.y + w10*Cv.y + w11*Dv.y;
    r.z = w00*A.z + w01*Bv.z + w10*Cv.z + w11*Dv.z;
    r.w = w00*A.w + w01*Bv.w + w10*Cv.w + w11*Dv.w;
    *(float4*)(dst + c) = r;
    *(ushort4*)(dsth + c) = make_ushort4(f2bf(r.x), f2bf(r.y), f2bf(r.z), f2bf(r.w));
  }
}

// QKV GEMM, bf16 MFMA. block=(window, 32-row tile); stages bf16 XBh via uint4
__global__ __launch_bounds__(256) void k_qkv(const ushort* __restrict__ XBh,
    const ushort* __restrict__ Wq, const float* __restrict__ in_b,
    const int* __restrict__ desc, ushort* __restrict__ Qs,
    ushort* __restrict__ Kb, ushort* __restrict__ Vb){
  int wi = blockIdx.x;
  if (((const int4*)desc)[wi].z == 0) return;
  int t0 = blockIdx.y * 32;
  __shared__ __align__(16) ushort Xs[32*264];
  int tid = threadIdx.x;
  const ushort* Ab = XBh + (size_t)(wi*256 + t0)*256;
  #pragma unroll
  for (int it = 0; it < 4; ++it){
    int i = tid + it*256;
    int row = i >> 5, k8 = (i & 31) * 8;
    *(uint4*)(&Xs[row*264 + k8]) = *(const uint4*)(Ab + row*256 + k8);
  }
  __syncthreads();
  int w = tid >> 6, l = tid & 63;
  int lr = l & 15, lg = l >> 4;
  f32x4 acc[2][12];
  #pragma unroll
  for (int a=0;a<2;++a)
    #pragma unroll
    for (int j=0;j<12;++j) acc[a][j] = (f32x4){0.f,0.f,0.f,0.f};
  for (int kc = 0; kc < 8; ++kc){
    short8v xf0 = *(const short8v*)(&Xs[lr*264       + kc*32 + lg*8]);
    short8v xf1 = *(const short8v*)(&Xs[(16+lr)*264 + kc*32 + lg*8]);
    #pragma unroll
    for (int jt = 0; jt < 12; ++jt){
      short8v wf = *(const short8v*)(Wq + ((size_t)((w*12 + jt)*8 + kc)*64 + l)*8);
      acc[0][jt] = __builtin_amdgcn_mfma_f32_16x16x32_bf16(xf0, wf, acc[0][jt], 0, 0, 0);
      acc[1][jt] = __builtin_amdgcn_mfma_f32_16x16x32_bf16(xf1, wf, acc[1][jt], 0, 0, 0);
    }
  }
  #pragma unroll
  for (int ts=0; ts<2; ++ts)
    #pragma unroll
    for (int jt=0; jt<12; ++jt){
      int j = w*192 + jt*16 + lr;
      #pragma unroll
      for (int r=0; r<4; ++r){
        int t = t0 + ts*16 + lg*4 + r;
        float val = acc[ts][jt][r] + in_b[j];
        if (j < 256){
          Qs[((size_t)(wi*256 + t))*256 + j] = f2bf(val * 0.17677669529663687f);
        } else if (j < 512){
          int jq = j - 256;
          Kb[((size_t)(wi*8 + (jq>>5))*256 + t)*32 + (jq&31)] = f2bf(val);
        } else {
          int jq = j - 512;
          Vb[((size_t)(wi*8 + (jq>>5))*256 + t)*32 + (jq&31)] = f2bf(val);
        }
      }
    }
}

// MFMA bf16 attention
__global__ __launch_bounds__(256,2) void k_attn(const ushort* __restrict__ Qs,
    const ushort* __restrict__ Kb, const ushort* __restrict__ Vb,
    const float* __restrict__ PEf, const int* __restrict__ desc,
    ushort* __restrict__ Ob){
  int wi = blockIdx.x, h = blockIdx.y;
  if (((const int4*)desc)[wi].z == 0) return;
  __shared__ __align__(16) ushort Ks[256*40];
  __shared__ __align__(16) ushort Vt[32*264];
  __shared__ __align__(16) ushort Pb[4][16*40];
  int tid = threadIdx.x;
  {
    const uint4* src = (const uint4*)(Kb + (size_t)((wi*8+h)*256 + tid)*32);
    uint4 a = src[0], b = src[1], c = src[2], d = src[3];
    *(uint4*)(&Ks[tid*40 +  0]) = a;
    *(uint4*)(&Ks[tid*40 +  8]) = b;
    *(uint4*)(&Ks[tid*40 + 16]) = c;
    *(uint4*)(&Ks[tid*40 + 24]) = d;
  }
  {
    const uint4* src = (const uint4*)(Vb + (size_t)((wi*8+h)*256 + tid)*32);
    #pragma unroll
    for (int c4=0; c4<4; ++c4){
      union{uint4 v; ushort u[8];} uu; uu.v = src[c4];
      #pragma unroll
      for (int e=0;e<8;++e) Vt[(c4*8+e)*264 + tid] = uu.u[e];
    }
  }
  __syncthreads();
  int w = tid >> 6, l = tid & 63;
  int lg = l >> 4, lr = l & 15;
  const float* PEh = PEf + h*65536;
  for (int s_i = 0; s_i < 4; ++s_i){
    int q0 = (w*4 + s_i)*16;
    short8v qf = *(const short8v*)(Qs + ((size_t)(wi*256 + q0 + lr))*256 + h*32 + lg*8);
    f32x4 sfr[16];
    #pragma unroll
    for (int jt=0; jt<16; ++jt){
      f32x4 c;
      #pragma unroll
      for (int r=0;r<4;++r) c[r] = PEh[(q0 + lg*4 + r)*256 + jt*16 + lr];
      short8v kf = *(const short8v*)(&Ks[(jt*16 + lr)*40 + lg*8]);
      sfr[jt] = __builtin_amdgcn_mfma_f32_16x16x32_bf16(qf, kf, c, 0, 0, 0);
    }
    float mx[4] = {-1e30f,-1e30f,-1e30f,-1e30f};
    #pragma unroll
    for (int jt=0;jt<16;++jt)
      #pragma unroll
      for (int r=0;r<4;++r) mx[r] = fmaxf(mx[r], sfr[jt][r]);
    #pragma unroll
    for (int m_=1; m_<16; m_<<=1){
      #pragma unroll
      for (int r=0;r<4;++r) mx[r] = fmaxf(mx[r], __shfl_xor(mx[r], m_));
    }
    float sm[4] = {0.f,0.f,0.f,0.f};
    #pragma unroll
    for (int jt=0;jt<16;++jt)
      #pragma unroll
      for (int r=0;r<4;++r){
        float p = __expf(sfr[jt][r] - mx[r]);
        sfr[jt][r] = p; sm[r] += p;
      }
    #pragma unroll
    for (int m_=1; m_<16; m_<<=1){
      #pragma unroll
      for (int r=0;r<4;++r) sm[r] += __shfl_xor(sm[r], m_);
    }
    f32x4 oa0 = {0.f,0.f,0.f,0.f}, oa1 = {0.f,0.f,0.f,0.f};
    ushort* pb = Pb[w];
    #pragma unroll
    for (int kc=0; kc<8; ++kc){
      #pragma unroll
      for (int t2=0;t2<2;++t2)
        #pragma unroll
        for (int r=0;r<4;++r)
          pb[(lg*4+r)*40 + t2*16 + lr] = f2bf(sfr[kc*2+t2][r]);
      short8v pf = *(const short8v*)(&pb[lr*40 + lg*8]);
      short8v v0 = *(const short8v*)(&Vt[lr*264 + kc*32 + lg*8]);
      short8v v1 = *(const short8v*)(&Vt[(16+lr)*264 + kc*32 + lg*8]);
      oa0 = __builtin_amdgcn_mfma_f32_16x16x32_bf16(pf, v0, oa0, 0, 0, 0);
      oa1 = __builtin_amdgcn_mfma_f32_16x16x32_bf16(pf, v1, oa1, 0, 0, 0);
    }
    #pragma unroll
    for (int r=0;r<4;++r){
      float inv = 1.0f / sm[r];
      size_t obase = ((size_t)(wi*256 + q0 + lg*4 + r))*256 + h*32;
      Ob[obase + lr]      = f2bf(oa0[r] * inv);
      Ob[obase + 16 + lr] = f2bf(oa1[r] * inv);
    }
  }
}

__global__ void k_zero(const int* __restrict__ desc, float* __restrict__ sums,
                       float* __restrict__ cnts){
  int wi = blockIdx.x;
  int4 d = ((const int4*)desc)[wi];
  if (!d.z) return;
  int b = wi >> 6;
  int t = threadIdx.x;
  int pix = (b*256 + d.x + (t>>4))*256 + d.y + (t&15);
  float4* p = (float4*)(sums + (size_t)pix*256);
  #pragma unroll 8
  for (int c=0;c<64;++c) p[c] = make_float4(0.f,0.f,0.f,0.f);
  atomicAdd(&cnts[pix], 1.0f);
}

// out-proj bf16 MFMA + delta + atomic scatter; x_before read fp32 (XBf)
__global__ __launch_bounds__(256) void k_oproj(const ushort* __restrict__ Ob,
    const ushort* __restrict__ Wq2, const float* __restrict__ out_b,
    const float* __restrict__ XBf, const int* __restrict__ desc,
    float* __restrict__ sums){
  int wi = blockIdx.x;
  int4 dsc = ((const int4*)desc)[wi];
  if (!dsc.z) return;
  int t0 = blockIdx.y * 32;
  __shared__ __align__(16) ushort Os[32*264];
  int tid = threadIdx.x;
  for (int i = tid; i < 1024; i += 256){
    int row = i >> 5, k8 = (i & 31) * 8;
    uint4 vv = *(const uint4*)(Ob + (size_t)(wi*256 + t0 + row)*256 + k8);
    *(uint4*)(&Os[row*264 + k8]) = vv;
  }
  __syncthreads();
  int w = tid >> 6, l = tid & 63;
  int lr = l & 15, lg = l >> 4;
  f32x4 acc[2][4];
  #pragma unroll
  for (int a=0;a<2;++a)
    #pragma unroll
    for (int j=0;j<4;++j) acc[a][j] = (f32x4){0.f,0.f,0.f,0.f};
  for (int kc = 0; kc < 8; ++kc){
    short8v of0 = *(const short8v*)(&Os[lr*264       + kc*32 + lg*8]);
    short8v of1 = *(const short8v*)(&Os[(16+lr)*264 + kc*32 + lg*8]);
    #pragma unroll
    for (int jt = 0; jt < 4; ++jt){
      short8v wf = *(const short8v*)(Wq2 + ((size_t)((w*4 + jt)*8 + kc)*64 + l)*8);
      acc[0][jt] = __builtin_amdgcn_mfma_f32_16x16x32_bf16(of0, wf, acc[0][jt], 0, 0, 0);
      acc[1][jt] = __builtin_amdgcn_mfma_f32_16x16x32_bf16(of1, wf, acc[1][jt], 0, 0, 0);
    }
  }
  int b = wi >> 6;
  #pragma unroll
  for (int ts=0; ts<2; ++ts)
    #pragma unroll
    for (int jt=0; jt<4; ++jt){
      int j = w*64 + jt*16 + lr;
      #pragma unroll
      for (int r=0; r<4; ++r){
        int t = t0 + ts*16 + lg*4 + r;
        int pix = (b*256 + dsc.x + (t>>4))*256 + dsc.y + (t&15);
        float delta = acc[ts][jt][r] + out_b[j] - XBf[((size_t)(wi*256 + t))*256 + j];
        atomicAdd(&sums[(size_t)pix*256 + j], delta);
      }
    }
}

// final depthwise 3x3 over (x + mean): block = (16-col tile, 2-row group, batch)
__global__ __launch_bounds__(256) void k_final(const float* __restrict__ x,
    const float* __restrict__ sums, const float* __restrict__ cnts,
    const float* __restrict__ ocw, const float* __restrict__ ocb,
    float* __restrict__ out){
  int x0 = blockIdx.x * 16;
  int y0 = blockIdx.y * 2;
  int b  = blockIdx.z;
  int c  = threadIdx.x;
  __shared__ float wl[2304];
  __shared__ float bl[256];
  __shared__ float invc[72];
  __shared__ int   anyc;
  if (threadIdx.x == 0) anyc = 0;
  for (int i = threadIdx.x; i < 2304; i += 256) wl[i] = ocw[i];
  bl[c] = ocb[c];
  __syncthreads();
  if (threadIdx.x < 72){
    int rr = threadIdx.x / 18, cc = threadIdx.x % 18;
    int yy = y0 + rr - 1, xx = x0 + cc - 1;
    float iv = 0.f;
    if ((unsigned)yy < 256u && (unsigned)xx < 256u){
      float cv = cnts[(b*256+yy)*256 + xx];
      if (cv > 0.f) iv = 1.0f / cv;
    }
    invc[threadIdx.x] = iv;
    if (iv != 0.f) anyc = 1;
  }
  float v[4][18];
  #pragma unroll
  for (int rr=0; rr<4; ++rr){
    int yy = y0 + rr - 1;
    int yc = min(max(yy, 0), 255);
    float ym = ((unsigned)yy < 256u) ? 1.f : 0.f;
    const float* rowb = x + ((size_t)((b*256+yc)*256))*256 + c;
    #pragma unroll
    for (int cc=0; cc<18; ++cc){
      int xx = x0 + cc - 1;
      int xc = min(max(xx, 0), 255);
      float m = ((unsigned)xx < 256u) ? ym : 0.f;
      v[rr][cc] = rowb[(size_t)xc*256] * m;
    }
  }
  #pragma unroll
  for (int rr=0; rr<4; ++rr)
    #pragma unroll
    for (int cc=0; cc<18; ++cc)
      asm volatile("" : "+v"(v[rr][cc]));
  __syncthreads();
  if (anyc){
    #pragma unroll
    for (int rr=0; rr<4; ++rr){
      int yy = y0 + rr - 1;
      int yc = min(max(yy, 0), 255);
      #pragma unroll
      for (int cc=0; cc<18; ++cc){
        int xx = x0 + cc - 1;
        int xc = min(max(xx, 0), 255);
        float iv = invc[rr*18 + cc];
        const float* bp = (iv != 0.f) ? sums : x;
        size_t idx = ((size_t)((b*256+yc)*256 + xc))*256 + c;
        v[rr][cc] += bp[idx] * iv;
      }
    }
  }
  float w0=wl[c*9+0], w1=wl[c*9+1], w2=wl[c*9+2],
        w3=wl[c*9+3], w4=wl[c*9+4], w5=wl[c*9+5],
        w6=wl[c*9+6], w7=wl[c*9+7], w8=wl[c*9+8];
  float bias = bl[c];
  #pragma unroll
  for (int r=0; r<2; ++r){
    size_t obase = ((size_t)((b*256+y0+r)*256 + x0))*256 + c;
    #pragma unroll
    for (int oc=0; oc<16; ++oc){
      float acc = bias
        + w0*v[r  ][oc] + w1*v[r  ][oc+1] + w2*v[r  ][oc+2]
        + w3*v[r+1][oc] + w4*v[r+1][oc+1] + w5*v[r+1][oc+2]
        + w6*v[r+2][oc] + w7*v[r+2][oc+1] + w8*v[r+2][oc+2];
      out[obase + (size_t)oc*256] = acc;
    }
  }
}

extern "C" void kernel_launch(void* const* d_in, const int* in_sizes, int n_in,
                              void* d_out, int out_size, void* d_ws, size_t ws_size,
                              hipStream_t stream){
  const float* x     = (const float*)d_in[0];
  const float* sd_w1 = (const float*)d_in[1];
  const float* sd_b1 = (const float*)d_in[2];
  const float* sd_w2 = (const float*)d_in[3];
  const float* sd_b2 = (const float*)d_in[4];
  const float* sd_w3 = (const float*)d_in[5];
  const float* sd_b3 = (const float*)d_in[6];
  const float* in_w  = (const float*)d_in[7];
  const float* in_b  = (const float*)d_in[8];
  const float* pe_t  = (const float*)d_in[9];
  const float* out_w = (const float*)d_in[10];
  const float* out_b = (const float*)d_in[11];
  const float* oc_w  = (const float*)d_in[12];
  const float* oc_b  = (const float*)d_in[13];
  float* out = (float*)d_out;
  char* ws = (char*)d_ws;
  if (ws_size < 204003328ULL) return;

  float*  w36 = (float*)(ws + 0);
  float*  t1  = (float*)(ws + 36864);
  float*  t2  = (float*)(ws + 2134016);
  int*    desc= (int*)  (ws + 2150400);
  ushort* Wq  = (ushort*)(ws + 2152448);
  ushort* Wq2 = (ushort*)(ws + 2545664);
  float*  XBf = (float*)(ws + 2676736);     // fp32 x_before
  float*  p36a= (float*)(ws + 2676736);     // aliases XBf (dead before k_xb)
  float*  p36b= (float*)(ws + 21551104);    // aliases XBf tail + Ob head
  ushort* Ob  = (ushort*)(ws + 36231168);
  float*  sums= (float*)(ws + 69261312);
  ushort* Qs  = (ushort*)(ws + 69261312);   // aliases sums (dead before k_zero)
  ushort* Kb  = (ushort*)(ws + 86038528);
  ushort* Vb  = (ushort*)(ws + 102815744);
  float*  PEf = (float*)(ws + 119592960);
  ushort* XBh = (ushort*)(ws + 121690112);  // bf16 x_before (dead before k_zero)
  float*  cnts= (float*)(ws + 203479040);

  k_prep <<<2276, 256, 0, stream>>>(sd_w1, w36, in_w, Wq, out_w, Wq2,
                                    pe_t, PEf, cnts);
  k_c1a  <<<dim3(512,2), 256, 0, stream>>>(x, w36, p36a, p36b);
  k_c1b  <<<512,  256, 0, stream>>>(p36a, p36b, sd_b1, t1);
  k_conv2<<<2048, 256, 0, stream>>>(t1, sd_w2, sd_b2, t2);
  k_sel  <<<2,    256, 0, stream>>>(t2, sd_w3, sd_b3, desc);
  k_xb   <<<dim3(128,16), 256, 0, stream>>>(x, desc, XBf, XBh);
  k_qkv  <<<dim3(128,8),  256, 0, stream>>>(XBh, Wq, in_b, desc, Qs, Kb, Vb);
  k_attn <<<dim3(128,8),  256, 0, stream>>>(Qs, Kb, Vb, PEf, desc, Ob);
  k_zero <<<128,  256, 0, stream>>>(desc, sums, cnts);
  k_oproj<<<dim3(128,8),  256, 0, stream>>>(Ob, Wq2, out_b, XBf, desc, sums);
  k_final<<<dim3(16,128,2),256, 0, stream>>>(x, sums, cnts, oc_w, oc_b, out);
}